// Round 1
// baseline (253.500 us; speedup 1.0000x reference)
//
#include <hip/hip_runtime.h>
#include <stdint.h>

#define TT 512
#define BB 32
#define EE 512
#define HH 2048

typedef __attribute__((ext_vector_type(8))) short short8;   // 8 x bf16 (4 VGPRs)
typedef __attribute__((ext_vector_type(4))) float f32x4;    // MFMA accumulator

static __device__ __forceinline__ unsigned short f2bf(float f) {
    union { float f; unsigned u; } v; v.f = f;
    unsigned u = v.u;
    unsigned r = u + 0x7FFFu + ((u >> 16) & 1u);   // round-to-nearest-even
    return (unsigned short)(r >> 16);
}

// ---------------------------------------------------------------------------
// Pre-kernel: convert sent (T,B,E) fp32 and W (3H,E) fp32 to bf16 in ws.
// ---------------------------------------------------------------------------
__global__ void convert_inputs(const float* __restrict__ X,
                               const float* __restrict__ W,
                               unsigned short* __restrict__ Xb,
                               unsigned short* __restrict__ Wb) {
    const int nX = TT * BB * EE;              // 8,388,608
    int i = (blockIdx.x * blockDim.x + threadIdx.x) * 4;
    const float* src;
    unsigned short* dst;
    int j;
    if (i < nX) { src = X; dst = Xb; j = i; }
    else        { src = W; dst = Wb; j = i - nX; }
    float4 v = *(const float4*)(src + j);
    ushort4 o;
    o.x = f2bf(v.x); o.y = f2bf(v.y); o.z = f2bf(v.z); o.w = f2bf(v.w);
    *(ushort4*)(dst + j) = o;
}

// ---------------------------------------------------------------------------
// Fused QRNN kernel.
// Block = (batch b, 64 h-columns). 4 waves x 16 h each. Wave-resident W frags.
// Per 16-t chunk: MFMA GEMM (z,f,o) -> activations -> in-register affine scan
// over t (shuffle-composed across quads) -> running max of o*c.
// ---------------------------------------------------------------------------
#define LDS_STRIDE 528   // shorts per LDS row: 512 + 16 pad (bank balance)

__launch_bounds__(256, 2)
__global__ void qrnn_fused(const unsigned short* __restrict__ Xb, // bf16 (T,B,E)
                           const unsigned short* __restrict__ Wb, // bf16 (3H,E)
                           const float* __restrict__ bias,        // (3H)
                           float* __restrict__ out)               // (B,H) fp32
{
    __shared__ unsigned short lds[2][16 * LDS_STRIDE];

    const int tid  = threadIdx.x;
    const int wv   = tid >> 6;         // wave 0..3
    const int lane = tid & 63;
    const int q    = lane >> 4;        // quad 0..3
    const int c    = lane & 15;        // column within 16x16 tile
    const int b    = blockIdx.y;
    const int h    = blockIdx.x * 64 + wv * 16 + c;   // this lane's h column

    // ---- preload W fragments into VGPRs (3 planes x 16 k-steps) ----
    // B-frag layout for 16x16x32: lane holds n = lane&15 (= h), k = q*8 + j.
    short8 wz[16], wf[16], wo[16];
    {
        const unsigned short* wzr = Wb + (size_t)h * EE;
        const unsigned short* wfr = Wb + (size_t)(HH + h) * EE;
        const unsigned short* wor = Wb + (size_t)(2 * HH + h) * EE;
#pragma unroll
        for (int k = 0; k < 16; ++k) {
            int e0 = k * 32 + q * 8;
            wz[k] = *(const short8*)(wzr + e0);
            wf[k] = *(const short8*)(wfr + e0);
            wo[k] = *(const short8*)(wor + e0);
        }
    }
    const float bz = bias[h];
    const float bf_ = bias[HH + h];
    const float bo = bias[2 * HH + h];

    float carry = 0.0f;      // c_{t-1} entering this chunk (per column)
    float vmax  = -1e30f;    // running max of o*c

    // staging: 256 threads copy 16 rows x 512 bf16 (global, coalesced 16B) to LDS
    auto stage = [&](int ch, int buf) {
        const int row  = tid >> 4;      // 0..15
        const int blk0 = tid & 15;      // 16B block id
        const unsigned short* src = Xb + ((size_t)(ch * 16 + row) * BB + b) * EE;
        unsigned short* dst = &lds[buf][row * LDS_STRIDE];
#pragma unroll
        for (int i = 0; i < 4; ++i) {
            int blk = blk0 + 16 * i;
            *(short8*)(dst + blk * 8) = *(const short8*)(src + blk * 8);
        }
    };

    stage(0, 0);
    __syncthreads();

    for (int ch = 0; ch < TT / 16; ++ch) {
        const int buf = ch & 1;
        if (ch + 1 < TT / 16) stage(ch + 1, buf ^ 1);

        // ---- GEMM for this chunk: A = X[t,:], B = W rows; 3 planes ----
        f32x4 az = {0.f, 0.f, 0.f, 0.f};
        f32x4 af = {0.f, 0.f, 0.f, 0.f};
        f32x4 ao = {0.f, 0.f, 0.f, 0.f};
        // A-frag layout: lane holds m = lane&15 (= t within chunk), k = q*8 + j
        const unsigned short* Abase = &lds[buf][c * LDS_STRIDE + q * 8];
#pragma unroll
        for (int k = 0; k < 16; ++k) {
            short8 a = *(const short8*)(Abase + k * 32);
            az = __builtin_amdgcn_mfma_f32_16x16x32_bf16(a, wz[k], az, 0, 0, 0);
            af = __builtin_amdgcn_mfma_f32_16x16x32_bf16(a, wf[k], af, 0, 0, 0);
            ao = __builtin_amdgcn_mfma_f32_16x16x32_bf16(a, wo[k], ao, 0, 0, 0);
        }

        // ---- activations: lane owns t = q*4 + r, column h ----
        float aa[4], mm[4], oo[4];
#pragma unroll
        for (int r = 0; r < 4; ++r) {
            float yz = az[r] + bz;
            float yf = af[r] + bf_;
            float yo = ao[r] + bo;
            float ez = __expf(-2.0f * yz);
            float z  = (1.0f - ez) / (1.0f + ez);          // tanh
            float f  = 1.0f / (1.0f + __expf(-yf));        // sigmoid
            float o  = 1.0f / (1.0f + __expf(-yo));        // sigmoid
            aa[r] = f * z;         // additive term
            mm[r] = 1.0f - f;      // multiplicative term
            oo[r] = o;
        }

        // ---- affine scan: compose lane's 4 steps, then scan across quads ----
        float A = aa[0], M = mm[0];
#pragma unroll
        for (int r = 1; r < 4; ++r) { A = aa[r] + mm[r] * A; M = mm[r] * M; }

        float Ap = __shfl_up(A, 16, 64), Mp = __shfl_up(M, 16, 64);
        if (q >= 1) { A = A + M * Ap; M = M * Mp; }
        Ap = __shfl_up(A, 32, 64); Mp = __shfl_up(M, 32, 64);
        if (q >= 2) { A = A + M * Ap; M = M * Mp; }
        // exclusive prefix for this lane's segment start
        float Ae = __shfl_up(A, 16, 64), Me = __shfl_up(M, 16, 64);
        if (q == 0) { Ae = 0.0f; Me = 1.0f; }
        float cc = Ae + Me * carry;

        // ---- replay the 4 steps exactly; track max(o*c) ----
#pragma unroll
        for (int r = 0; r < 4; ++r) {
            cc = aa[r] + mm[r] * cc;
            vmax = fmaxf(vmax, oo[r] * cc);
        }

        // carry out = chunk-end c (q==3 lane's inclusive transform on carry)
        float cend = A + M * carry;
        carry = __shfl(cend, 48 + c, 64);

        __syncthreads();   // staging of ch+1 done AND buf safe to overwrite
    }

    // reduce max across the 4 quads of each column
    vmax = fmaxf(vmax, __shfl_xor(vmax, 16, 64));
    vmax = fmaxf(vmax, __shfl_xor(vmax, 32, 64));
    if (q == 0) out[(size_t)b * HH + h] = vmax;
}

// ---------------------------------------------------------------------------
extern "C" void kernel_launch(void* const* d_in, const int* in_sizes, int n_in,
                              void* d_out, int out_size, void* d_ws, size_t ws_size,
                              hipStream_t stream) {
    const float* sent = (const float*)d_in[0];
    // d_in[1] = lengths (unused by the math)
    const float* W    = (const float*)d_in[2];
    const float* bias = (const float*)d_in[3];
    float* out        = (float*)d_out;

    const int nX = TT * BB * EE;        // 8,388,608
    const int nW = 3 * HH * EE;         // 3,145,728
    unsigned short* Xb = (unsigned short*)d_ws;
    unsigned short* Wb = Xb + nX;       // 16 MiB offset, 16B-aligned

    int totalVec = (nX + nW) / 4;       // 2,883,584 threads, exact cover
    convert_inputs<<<totalVec / 256, 256, 0, stream>>>(sent, W, Xb, Wb);

    dim3 grid(HH / 64, BB);             // (32, 32) = 1024 blocks
    qrnn_fused<<<grid, 256, 0, stream>>>(Xb, Wb, bias, out);
}